// Round 1
// baseline (3999.987 us; speedup 1.0000x reference)
//
#include <hip/hip_runtime.h>
#include <math.h>

#define N_NODES 20000
#define N_EDGES 320000
#define H 256
#define GH 512
#define G3 768
#define NT 3
#define R_ROUNDS 2

// ---------------------------------------------------------------- scatter
// S[dst] += hv[src]; deg[dst] += 1; hesum[dst] += he[e].  One wave per edge.
__global__ __launch_bounds__(256) void scatter_kernel(
    const float* __restrict__ hv, const float* __restrict__ he,
    const int* __restrict__ src, const int* __restrict__ dst,
    float* __restrict__ S, float* __restrict__ deg, float* __restrict__ hesum) {
  int w = (blockIdx.x * blockDim.x + threadIdx.x) >> 6;
  int lane = threadIdx.x & 63;
  if (w >= N_EDGES) return;
  int s = src[w], d = dst[w];
  const float4 v = *reinterpret_cast<const float4*>(hv + (size_t)s * H + lane * 4);
  float* p = S + (size_t)d * H + lane * 4;
  unsafeAtomicAdd(p + 0, v.x);
  unsafeAtomicAdd(p + 1, v.y);
  unsafeAtomicAdd(p + 2, v.z);
  unsafeAtomicAdd(p + 3, v.w);
  if (lane == 0) {
    unsafeAtomicAdd(deg + d, 1.0f);
    unsafeAtomicAdd(hesum + d, he[w]);
  }
}

// ---------------------------------------------------------------- msg GEMM
// C[i][j] = sum_k Avirt[i][k] * Wm[k][j] + hesum[i]*Wm[512][j] + deg[i]*bm[j]
// Avirt[i][k] = k<256 ? deg[i]*hv[i][k] : S[i][k-256].  M=20000, N=512, K=512.
__global__ __launch_bounds__(256) void msg_gemm(
    const float* __restrict__ hv, const float* __restrict__ S,
    const float* __restrict__ deg, const float* __restrict__ hesum,
    const float* __restrict__ Wm,  // 513 x 512 row-major
    const float* __restrict__ bm,  // 512
    float* __restrict__ C) {
  __shared__ float As[16][65];
  __shared__ float Bs[16][65];
  const int M = N_NODES;
  int i0 = blockIdx.y * 64, j0 = blockIdx.x * 64;
  int t = threadIdx.x;
  int lm = t >> 2, kq = t & 3;   // A-load / B^T-load mapping
  int jq = t & 15, kr = t >> 4;  // B-load mapping (K x N row-major)
  int tx = t & 15, ty = t >> 4;  // compute mapping
  float acc[4][4] = {};
  for (int k0 = 0; k0 < GH; k0 += 16) {
    int row = i0 + lm;
    float4 v = make_float4(0.f, 0.f, 0.f, 0.f);
    if (row < M) {
      if (k0 < H) {
        v = *reinterpret_cast<const float4*>(hv + (size_t)row * H + k0 + kq * 4);
        float dg = deg[row];
        v.x *= dg; v.y *= dg; v.z *= dg; v.w *= dg;
      } else {
        v = *reinterpret_cast<const float4*>(S + (size_t)row * H + (k0 - H) + kq * 4);
      }
    }
    As[kq * 4 + 0][lm] = v.x; As[kq * 4 + 1][lm] = v.y;
    As[kq * 4 + 2][lm] = v.z; As[kq * 4 + 3][lm] = v.w;
    float4 w = *reinterpret_cast<const float4*>(Wm + (size_t)(k0 + kr) * GH + j0 + jq * 4);
    Bs[kr][jq * 4 + 0] = w.x; Bs[kr][jq * 4 + 1] = w.y;
    Bs[kr][jq * 4 + 2] = w.z; Bs[kr][jq * 4 + 3] = w.w;
    __syncthreads();
#pragma unroll
    for (int kk = 0; kk < 16; kk++) {
      float a0 = As[kk][ty * 4 + 0], a1 = As[kk][ty * 4 + 1];
      float a2 = As[kk][ty * 4 + 2], a3 = As[kk][ty * 4 + 3];
      float b0 = Bs[kk][tx * 4 + 0], b1 = Bs[kk][tx * 4 + 1];
      float b2 = Bs[kk][tx * 4 + 2], b3 = Bs[kk][tx * 4 + 3];
      acc[0][0] += a0 * b0; acc[0][1] += a0 * b1; acc[0][2] += a0 * b2; acc[0][3] += a0 * b3;
      acc[1][0] += a1 * b0; acc[1][1] += a1 * b1; acc[1][2] += a1 * b2; acc[1][3] += a1 * b3;
      acc[2][0] += a2 * b0; acc[2][1] += a2 * b1; acc[2][2] += a2 * b2; acc[2][3] += a2 * b3;
      acc[3][0] += a3 * b0; acc[3][1] += a3 * b1; acc[3][2] += a3 * b2; acc[3][3] += a3 * b3;
    }
    __syncthreads();
  }
  const float* we = Wm + (size_t)GH * GH;  // row 512
#pragma unroll
  for (int r = 0; r < 4; r++) {
    int row = i0 + ty * 4 + r;
    if (row >= M) continue;
    float dg = deg[row], hs = hesum[row];
#pragma unroll
    for (int c = 0; c < 4; c++) {
      int col = j0 + tx * 4 + c;
      C[(size_t)row * GH + col] = acc[r][c] + hs * we[col] + dg * bm[col];
    }
  }
}

// ---------------------------------------------------------------- generic GEMM
// C[M x Nc] = A[M x K] @ W^T + bias, with W given (Nc x K) row-major.
__global__ __launch_bounds__(256) void gemm_bt_bias(
    int M, int Nc, int K,
    const float* __restrict__ A, int lda,
    const float* __restrict__ W, const float* __restrict__ bias,
    float* __restrict__ C, int ldc) {
  __shared__ float As[16][65];
  __shared__ float Bs[16][65];
  int i0 = blockIdx.y * 64, j0 = blockIdx.x * 64;
  int t = threadIdx.x;
  int lm = t >> 2, kq = t & 3;
  int tx = t & 15, ty = t >> 4;
  float acc[4][4] = {};
  for (int k0 = 0; k0 < K; k0 += 16) {
    {
      int row = i0 + lm;
      float4 v = make_float4(0.f, 0.f, 0.f, 0.f);
      if (row < M) v = *reinterpret_cast<const float4*>(A + (size_t)row * lda + k0 + kq * 4);
      As[kq * 4 + 0][lm] = v.x; As[kq * 4 + 1][lm] = v.y;
      As[kq * 4 + 2][lm] = v.z; As[kq * 4 + 3][lm] = v.w;
    }
    {
      int col = j0 + lm;  // Nc divisible by 64 -> no guard
      float4 v = *reinterpret_cast<const float4*>(W + (size_t)col * K + k0 + kq * 4);
      Bs[kq * 4 + 0][lm] = v.x; Bs[kq * 4 + 1][lm] = v.y;
      Bs[kq * 4 + 2][lm] = v.z; Bs[kq * 4 + 3][lm] = v.w;
    }
    __syncthreads();
#pragma unroll
    for (int kk = 0; kk < 16; kk++) {
      float a0 = As[kk][ty * 4 + 0], a1 = As[kk][ty * 4 + 1];
      float a2 = As[kk][ty * 4 + 2], a3 = As[kk][ty * 4 + 3];
      float b0 = Bs[kk][tx * 4 + 0], b1 = Bs[kk][tx * 4 + 1];
      float b2 = Bs[kk][tx * 4 + 2], b3 = Bs[kk][tx * 4 + 3];
      acc[0][0] += a0 * b0; acc[0][1] += a0 * b1; acc[0][2] += a0 * b2; acc[0][3] += a0 * b3;
      acc[1][0] += a1 * b0; acc[1][1] += a1 * b1; acc[1][2] += a1 * b2; acc[1][3] += a1 * b3;
      acc[2][0] += a2 * b0; acc[2][1] += a2 * b1; acc[2][2] += a2 * b2; acc[2][3] += a2 * b3;
      acc[3][0] += a3 * b0; acc[3][1] += a3 * b1; acc[3][2] += a3 * b2; acc[3][3] += a3 * b3;
    }
    __syncthreads();
  }
#pragma unroll
  for (int r = 0; r < 4; r++) {
    int row = i0 + ty * 4 + r;
    if (row >= M) continue;
#pragma unroll
    for (int c = 0; c < 4; c++) {
      int col = j0 + tx * 4 + c;
      C[(size_t)row * ldc + col] = acc[r][c] + bias[col];
    }
  }
}

// ---------------------------------------------------------------- GRU elementwise
__global__ void gru_update(const float* __restrict__ gi, const float* __restrict__ gh,
                           float* __restrict__ hv) {
  int idx = blockIdx.x * blockDim.x + threadIdx.x;
  if (idx >= N_NODES * H) return;
  int row = idx >> 8, col = idx & 255;
  const float* gir = gi + (size_t)row * G3;
  const float* ghr = gh + (size_t)row * G3;
  float ir = gir[col], iz = gir[H + col], inn = gir[2 * H + col];
  float hr = ghr[col], hz = ghr[H + col], hn = ghr[2 * H + col];
  float r = 1.f / (1.f + expf(-(ir + hr)));
  float z = 1.f / (1.f + expf(-(iz + hz)));
  float n = tanhf(inn + r * hn);
  hv[idx] = (1.f - z) * n + z * hv[idx];
}

// ---------------------------------------------------------------- graph embed phase 1
// U[t][k] = sum_{i: ntype=t} g_i * hv[i][k];   G[t] = sum g_i
__global__ __launch_bounds__(256) void embed_phase1(
    const float* __restrict__ hv, const int* __restrict__ ntype,
    const float* __restrict__ gate_w, const float* __restrict__ gate_b,
    float* __restrict__ U, float* __restrict__ G) {
  __shared__ float Ul[NT * H];
  __shared__ float Gl[NT];
  for (int j = threadIdx.x; j < NT * H; j += 256) Ul[j] = 0.f;
  if (threadIdx.x < NT) Gl[threadIdx.x] = 0.f;
  __syncthreads();
  int lane = threadIdx.x & 63;
  int wave = blockIdx.x * 4 + (threadIdx.x >> 6);
  int nwaves = gridDim.x * 4;
  for (int i = wave; i < N_NODES; i += nwaves) {
    int t = ntype[i];
    float4 h = *reinterpret_cast<const float4*>(hv + (size_t)i * H + lane * 4);
    float4 w = *reinterpret_cast<const float4*>(gate_w + t * H + lane * 4);
    float s = h.x * w.x + h.y * w.y + h.z * w.z + h.w * w.w;
    for (int off = 32; off; off >>= 1) s += __shfl_xor(s, off);
    float g = 1.f / (1.f + expf(-(s + gate_b[t])));
    float* up = Ul + t * H + lane * 4;
    atomicAdd(up + 0, g * h.x);
    atomicAdd(up + 1, g * h.y);
    atomicAdd(up + 2, g * h.z);
    atomicAdd(up + 3, g * h.w);
    if (lane == 0) atomicAdd(&Gl[t], g);
  }
  __syncthreads();
  for (int j = threadIdx.x; j < NT * H; j += 256) unsafeAtomicAdd(&U[j], Ul[j]);
  if (threadIdx.x < NT) unsafeAtomicAdd(&G[threadIdx.x], Gl[threadIdx.x]);
}

// ---------------------------------------------------------------- small heads (1 block)
__global__ __launch_bounds__(512) void small_head(
    const float* __restrict__ U, const float* __restrict__ G,
    const float* __restrict__ tograph_w, const float* __restrict__ tograph_b,
    const float* __restrict__ addnode_w, const float* __restrict__ addnode_b,
    const float* __restrict__ ntype_embed, const float* __restrict__ inithv_w,
    const float* __restrict__ inithv_b, const float* __restrict__ addedge_w,
    const float* __restrict__ addedge_b, const float* __restrict__ hv,
    const float* __restrict__ dest_w, const float* __restrict__ dest_b,
    float* __restrict__ gembed_out, float* __restrict__ nodelogp_out,
    float* __restrict__ hvinit_out, float* __restrict__ edgelogit_out,
    float* __restrict__ misc) {
  __shared__ float ge[GH];
  __shared__ float lg[8];
  int tid = threadIdx.x;
  {  // gembed[j] = sum_t (U[t] @ tograph_w[t])[j] + G[t]*tograph_b[t][j]
    float acc = 0.f;
    for (int t = 0; t < NT; t++) {
      const float* Wt = tograph_w + (size_t)t * H * GH;
      float a2 = 0.f;
      for (int k = 0; k < H; k++) a2 += U[t * H + k] * Wt[(size_t)k * GH + tid];
      acc += a2 + G[t] * tograph_b[t * GH + tid];
    }
    ge[tid] = acc;
    gembed_out[tid] = acc;
  }
  __syncthreads();
  if (tid < 4) {  // node logits
    float l = addnode_b[tid];
    for (int k = 0; k < GH; k++) l += ge[k] * addnode_w[k * 4 + tid];
    lg[tid] = l;
  }
  __syncthreads();
  if (tid == 0) {  // log_softmax over 4
    float m = fmaxf(fmaxf(lg[0], lg[1]), fmaxf(lg[2], lg[3]));
    float s = 0.f;
    for (int c = 0; c < 4; c++) s += expf(lg[c] - m);
    float lse = m + logf(s);
    for (int c = 0; c < 4; c++) nodelogp_out[c] = lg[c] - lse;
  }
  if (tid < H) {  // hv_init = [ntype_embed[0] | gembed] @ inithv_w + b
    float s = inithv_b[tid];
    for (int k = 0; k < H; k++) s += ntype_embed[k] * inithv_w[(size_t)k * H + tid];
    for (int k = 0; k < GH; k++) s += ge[k] * inithv_w[(size_t)(H + k) * H + tid];
    hvinit_out[tid] = s;
  }
  if (tid >= 256 && tid < 320) {  // edge_logit = [gembed | src_embed] . addedge_w + b
    int lane = tid - 256;
    const float* se = hv + (size_t)(N_NODES - 1) * H;
    float s = 0.f;
    for (int k = lane; k < G3; k += 64) {
      float x = (k < GH) ? ge[k] : se[k - GH];
      s += x * addedge_w[k];
    }
    for (int off = 32; off; off >>= 1) s += __shfl_xor(s, off);
    if (lane == 0) edgelogit_out[0] = s + addedge_b[0];
  }
  if (tid >= 320 && tid < 384) {  // c2 = src_embed . dest_w[256:512] + dest_b
    int lane = tid - 320;
    const float* se = hv + (size_t)(N_NODES - 1) * H;
    float s = 0.f;
    for (int k = lane; k < H; k += 64) s += se[k] * dest_w[H + k];
    for (int off = 32; off; off >>= 1) s += __shfl_xor(s, off);
    if (lane == 0) misc[0] = s + dest_b[0];
  }
}

// ---------------------------------------------------------------- dest scores
__global__ __launch_bounds__(256) void dest_scores_kernel(
    const float* __restrict__ hv, const float* __restrict__ dest_w,
    const float* __restrict__ misc, float* __restrict__ scores) {
  int w = (blockIdx.x * blockDim.x + threadIdx.x) >> 6;
  int lane = threadIdx.x & 63;
  if (w >= N_NODES - 1) return;
  float4 h = *reinterpret_cast<const float4*>(hv + (size_t)w * H + lane * 4);
  float4 d = *reinterpret_cast<const float4*>(dest_w + lane * 4);
  float s = h.x * d.x + h.y * d.y + h.z * d.z + h.w * d.w;
  for (int off = 32; off; off >>= 1) s += __shfl_xor(s, off);
  if (lane == 0) scores[w] = s + misc[0];
}

// ---------------------------------------------------------------- dest log_softmax
__global__ __launch_bounds__(1024) void dest_softmax(const float* __restrict__ scores,
                                                     float* __restrict__ out) {
  const int n = N_NODES - 1;
  __shared__ float red[16];
  __shared__ float bc[2];
  int tid = threadIdx.x;
  float m = -1e30f;
  for (int i = tid; i < n; i += 1024) m = fmaxf(m, scores[i]);
  for (int off = 32; off; off >>= 1) m = fmaxf(m, __shfl_xor(m, off));
  if ((tid & 63) == 0) red[tid >> 6] = m;
  __syncthreads();
  if (tid == 0) {
    float v = red[0];
    for (int i = 1; i < 16; i++) v = fmaxf(v, red[i]);
    bc[0] = v;
  }
  __syncthreads();
  float mx = bc[0];
  float s = 0.f;
  for (int i = tid; i < n; i += 1024) s += expf(scores[i] - mx);
  for (int off = 32; off; off >>= 1) s += __shfl_xor(s, off);
  if ((tid & 63) == 0) red[tid >> 6] = s;
  __syncthreads();
  if (tid == 0) {
    float v = 0.f;
    for (int i = 0; i < 16; i++) v += red[i];
    bc[1] = v;
  }
  __syncthreads();
  float lse = mx + logf(bc[1]);
  for (int i = tid; i < n; i += 1024) out[i] = scores[i] - lse;
}

// ---------------------------------------------------------------- launch
extern "C" void kernel_launch(void* const* d_in, const int* in_sizes, int n_in,
                              void* d_out, int out_size, void* d_ws, size_t ws_size,
                              hipStream_t stream) {
  const float* hv0 = (const float*)d_in[0];
  const float* he = (const float*)d_in[1];
  const int* ntype = (const int*)d_in[2];
  const int* src = (const int*)d_in[3];
  const int* dst = (const int*)d_in[4];
  const float* msg_w = (const float*)d_in[5];
  const float* msg_b = (const float*)d_in[6];
  const float* w_ih = (const float*)d_in[7];
  const float* b_ih = (const float*)d_in[8];
  const float* w_hh = (const float*)d_in[9];
  const float* b_hh = (const float*)d_in[10];
  const float* gate_w = (const float*)d_in[11];
  const float* gate_b = (const float*)d_in[12];
  const float* tograph_w = (const float*)d_in[13];
  const float* tograph_b = (const float*)d_in[14];
  const float* addnode_w = (const float*)d_in[15];
  const float* addnode_b = (const float*)d_in[16];
  const float* ntype_embed = (const float*)d_in[17];
  const float* inithv_w = (const float*)d_in[18];
  const float* inithv_b = (const float*)d_in[19];
  const float* addedge_w = (const float*)d_in[20];
  const float* addedge_b = (const float*)d_in[21];
  const float* dest_w = (const float*)d_in[22];
  const float* dest_b = (const float*)d_in[23];

  float* out = (float*)d_out;
  float* HV = out;                                   // N*H (working hv, also output 0)
  float* gembed_out = out + (size_t)N_NODES * H;     // 512
  float* nodelogp_out = gembed_out + GH;             // 4
  float* hvinit_out = nodelogp_out + 4;              // 256
  float* edgelogit_out = hvinit_out + H;             // 1
  float* destlogp_out = edgelogit_out + 1;           // N-1

  float* ws = (float*)d_ws;
  float* S = ws;                                     // N*H
  float* deg = S + (size_t)N_NODES * H;              // N
  float* hesum = deg + N_NODES;                      // N
  float* a_buf = hesum + N_NODES;                    // N*GH
  float* gi = a_buf + (size_t)N_NODES * GH;          // N*G3
  float* gh = gi + (size_t)N_NODES * G3;             // N*G3
  float* U = gh + (size_t)N_NODES * G3;              // NT*H
  float* G = U + NT * H;                             // NT
  float* misc = G + NT;                              // 16
  float* scores = misc + 16;                         // N-1

  hipMemcpyAsync(HV, hv0, sizeof(float) * (size_t)N_NODES * H,
                 hipMemcpyDeviceToDevice, stream);

  for (int t = 0; t < R_ROUNDS; t++) {
    // zero S, deg, hesum (contiguous)
    hipMemsetAsync(S, 0, sizeof(float) * ((size_t)N_NODES * H + 2 * N_NODES), stream);
    scatter_kernel<<<N_EDGES / 4, 256, 0, stream>>>(HV, he, src, dst, S, deg, hesum);
    {
      dim3 grid(GH / 64, (N_NODES + 63) / 64);
      msg_gemm<<<grid, 256, 0, stream>>>(HV, S, deg, hesum,
                                         msg_w + (size_t)t * (2 * H + 1) * GH,
                                         msg_b + (size_t)t * GH, a_buf);
    }
    {
      dim3 grid(G3 / 64, (N_NODES + 63) / 64);
      gemm_bt_bias<<<grid, 256, 0, stream>>>(N_NODES, G3, GH, a_buf, GH,
                                             w_ih + (size_t)t * G3 * GH,
                                             b_ih + (size_t)t * G3, gi, G3);
      gemm_bt_bias<<<grid, 256, 0, stream>>>(N_NODES, G3, H, HV, H,
                                             w_hh + (size_t)t * G3 * H,
                                             b_hh + (size_t)t * G3, gh, G3);
    }
    gru_update<<<(N_NODES * H + 255) / 256, 256, 0, stream>>>(gi, gh, HV);
  }

  hipMemsetAsync(U, 0, sizeof(float) * (NT * H + NT), stream);
  embed_phase1<<<128, 256, 0, stream>>>(HV, ntype, gate_w, gate_b, U, G);
  small_head<<<1, 512, 0, stream>>>(U, G, tograph_w, tograph_b, addnode_w, addnode_b,
                                    ntype_embed, inithv_w, inithv_b, addedge_w,
                                    addedge_b, HV, dest_w, dest_b, gembed_out,
                                    nodelogp_out, hvinit_out, edgelogit_out, misc);
  dest_scores_kernel<<<((N_NODES - 1) * 64 + 255) / 256, 256, 0, stream>>>(
      HV, dest_w, misc, scores);
  dest_softmax<<<1, 1024, 0, stream>>>(scores, destlogp_out);
}

// Round 2
// 1846.694 us; speedup vs baseline: 2.1660x; 2.1660x over previous
//
#include <hip/hip_runtime.h>
#include <math.h>

#define N_NODES 20000
#define N_EDGES 320000
#define H 256
#define GH 512
#define G3 768
#define NT 3
#define R_ROUNDS 2

// ---------------------------------------------------------------- CSR build
__global__ __launch_bounds__(256) void hist_kernel(
    const int* __restrict__ dst, const float* __restrict__ he,
    int* __restrict__ cnt, float* __restrict__ hesum) {
  int e = blockIdx.x * 256 + threadIdx.x;
  if (e >= N_EDGES) return;
  int d = dst[e];
  atomicAdd(&cnt[d], 1);
  unsafeAtomicAdd(&hesum[d], he[e]);
}

// single-block exclusive scan over N_NODES counts -> rowptr, cursor
__global__ __launch_bounds__(1024) void scan_kernel(
    const int* __restrict__ cnt, int* __restrict__ rowptr, int* __restrict__ cursor) {
  __shared__ int part[1024];
  const int CH = (N_NODES + 1023) / 1024;  // 20
  int t = threadIdx.x;
  int base = t * CH;
  int s = 0;
  for (int j = 0; j < CH; j++) {
    int idx = base + j;
    if (idx < N_NODES) s += cnt[idx];
  }
  part[t] = s;
  __syncthreads();
  // simple log-step exclusive scan of partials
  int v = part[t];
  for (int off = 1; off < 1024; off <<= 1) {
    int o = (t >= off) ? part[t - off] : 0;
    __syncthreads();
    part[t] += o;
    __syncthreads();
  }
  int excl = part[t] - v;  // exclusive prefix of this chunk
  int run = excl;
  for (int j = 0; j < CH; j++) {
    int idx = base + j;
    if (idx < N_NODES) {
      rowptr[idx] = run;
      cursor[idx] = run;
      run += cnt[idx];
    }
  }
  if (t == 1023) rowptr[N_NODES] = run;
}

__global__ __launch_bounds__(256) void fill_kernel(
    const int* __restrict__ dst, const int* __restrict__ src,
    int* __restrict__ cursor, int* __restrict__ nbr) {
  int e = blockIdx.x * 256 + threadIdx.x;
  if (e >= N_EDGES) return;
  int p = atomicAdd(&cursor[dst[e]], 1);
  nbr[p] = src[e];
}

// ---------------------------------------------------------------- gather
// S[i] = sum_{neighbors s} hv[s]; deg[i] = row length. One wave per node.
__global__ __launch_bounds__(256) void gather_kernel(
    const float* __restrict__ hv, const int* __restrict__ rowptr,
    const int* __restrict__ nbr, float* __restrict__ S, float* __restrict__ deg) {
  int w = (blockIdx.x * blockDim.x + threadIdx.x) >> 6;
  int lane = threadIdx.x & 63;
  if (w >= N_NODES) return;
  int start = rowptr[w], end = rowptr[w + 1];
  float4 acc = make_float4(0.f, 0.f, 0.f, 0.f);
  for (int b = start; b < end; b += 64) {
    int nb = min(64, end - b);
    int sidx = (lane < nb) ? nbr[b + lane] : 0;
    for (int j = 0; j < nb; j++) {
      int s = __shfl(sidx, j);
      const float4 v = *reinterpret_cast<const float4*>(hv + (size_t)s * H + lane * 4);
      acc.x += v.x; acc.y += v.y; acc.z += v.z; acc.w += v.w;
    }
  }
  *reinterpret_cast<float4*>(S + (size_t)w * H + lane * 4) = acc;
  if (lane == 0) deg[w] = (float)(end - start);
}

// ---------------------------------------------------------------- msg GEMM
// C[i][j] = sum_k Avirt[i][k] * Wm[k][j] + hesum[i]*Wm[512][j] + deg[i]*bm[j]
// Avirt[i][k] = k<256 ? deg[i]*hv[i][k] : S[i][k-256].  M=20000, N=512, K=512.
__global__ __launch_bounds__(256) void msg_gemm(
    const float* __restrict__ hv, const float* __restrict__ S,
    const float* __restrict__ deg, const float* __restrict__ hesum,
    const float* __restrict__ Wm,  // 513 x 512 row-major
    const float* __restrict__ bm,  // 512
    float* __restrict__ C) {
  __shared__ float As[16][65];
  __shared__ float Bs[16][65];
  const int M = N_NODES;
  int i0 = blockIdx.y * 64, j0 = blockIdx.x * 64;
  int t = threadIdx.x;
  int lm = t >> 2, kq = t & 3;   // A-load mapping
  int jq = t & 15, kr = t >> 4;  // B-load mapping (K x N row-major)
  int tx = t & 15, ty = t >> 4;  // compute mapping
  float acc[4][4] = {};
  for (int k0 = 0; k0 < GH; k0 += 16) {
    int row = i0 + lm;
    float4 v = make_float4(0.f, 0.f, 0.f, 0.f);
    if (row < M) {
      if (k0 < H) {
        v = *reinterpret_cast<const float4*>(hv + (size_t)row * H + k0 + kq * 4);
        float dg = deg[row];
        v.x *= dg; v.y *= dg; v.z *= dg; v.w *= dg;
      } else {
        v = *reinterpret_cast<const float4*>(S + (size_t)row * H + (k0 - H) + kq * 4);
      }
    }
    As[kq * 4 + 0][lm] = v.x; As[kq * 4 + 1][lm] = v.y;
    As[kq * 4 + 2][lm] = v.z; As[kq * 4 + 3][lm] = v.w;
    float4 w = *reinterpret_cast<const float4*>(Wm + (size_t)(k0 + kr) * GH + j0 + jq * 4);
    Bs[kr][jq * 4 + 0] = w.x; Bs[kr][jq * 4 + 1] = w.y;
    Bs[kr][jq * 4 + 2] = w.z; Bs[kr][jq * 4 + 3] = w.w;
    __syncthreads();
#pragma unroll
    for (int kk = 0; kk < 16; kk++) {
      float a0 = As[kk][ty * 4 + 0], a1 = As[kk][ty * 4 + 1];
      float a2 = As[kk][ty * 4 + 2], a3 = As[kk][ty * 4 + 3];
      float b0 = Bs[kk][tx * 4 + 0], b1 = Bs[kk][tx * 4 + 1];
      float b2 = Bs[kk][tx * 4 + 2], b3 = Bs[kk][tx * 4 + 3];
      acc[0][0] += a0 * b0; acc[0][1] += a0 * b1; acc[0][2] += a0 * b2; acc[0][3] += a0 * b3;
      acc[1][0] += a1 * b0; acc[1][1] += a1 * b1; acc[1][2] += a1 * b2; acc[1][3] += a1 * b3;
      acc[2][0] += a2 * b0; acc[2][1] += a2 * b1; acc[2][2] += a2 * b2; acc[2][3] += a2 * b3;
      acc[3][0] += a3 * b0; acc[3][1] += a3 * b1; acc[3][2] += a3 * b2; acc[3][3] += a3 * b3;
    }
    __syncthreads();
  }
  const float* we = Wm + (size_t)GH * GH;  // row 512
#pragma unroll
  for (int r = 0; r < 4; r++) {
    int row = i0 + ty * 4 + r;
    if (row >= M) continue;
    float dg = deg[row], hs = hesum[row];
#pragma unroll
    for (int c = 0; c < 4; c++) {
      int col = j0 + tx * 4 + c;
      C[(size_t)row * GH + col] = acc[r][c] + hs * we[col] + dg * bm[col];
    }
  }
}

// ---------------------------------------------------------------- generic GEMM
// C[M x Nc] = A[M x K] @ W^T + bias, with W given (Nc x K) row-major.
__global__ __launch_bounds__(256) void gemm_bt_bias(
    int M, int Nc, int K,
    const float* __restrict__ A, int lda,
    const float* __restrict__ W, const float* __restrict__ bias,
    float* __restrict__ C, int ldc) {
  __shared__ float As[16][65];
  __shared__ float Bs[16][65];
  int i0 = blockIdx.y * 64, j0 = blockIdx.x * 64;
  int t = threadIdx.x;
  int lm = t >> 2, kq = t & 3;
  int tx = t & 15, ty = t >> 4;
  float acc[4][4] = {};
  for (int k0 = 0; k0 < K; k0 += 16) {
    {
      int row = i0 + lm;
      float4 v = make_float4(0.f, 0.f, 0.f, 0.f);
      if (row < M) v = *reinterpret_cast<const float4*>(A + (size_t)row * lda + k0 + kq * 4);
      As[kq * 4 + 0][lm] = v.x; As[kq * 4 + 1][lm] = v.y;
      As[kq * 4 + 2][lm] = v.z; As[kq * 4 + 3][lm] = v.w;
    }
    {
      int col = j0 + lm;  // Nc divisible by 64 -> no guard
      float4 v = *reinterpret_cast<const float4*>(W + (size_t)col * K + k0 + kq * 4);
      Bs[kq * 4 + 0][lm] = v.x; Bs[kq * 4 + 1][lm] = v.y;
      Bs[kq * 4 + 2][lm] = v.z; Bs[kq * 4 + 3][lm] = v.w;
    }
    __syncthreads();
#pragma unroll
    for (int kk = 0; kk < 16; kk++) {
      float a0 = As[kk][ty * 4 + 0], a1 = As[kk][ty * 4 + 1];
      float a2 = As[kk][ty * 4 + 2], a3 = As[kk][ty * 4 + 3];
      float b0 = Bs[kk][tx * 4 + 0], b1 = Bs[kk][tx * 4 + 1];
      float b2 = Bs[kk][tx * 4 + 2], b3 = Bs[kk][tx * 4 + 3];
      acc[0][0] += a0 * b0; acc[0][1] += a0 * b1; acc[0][2] += a0 * b2; acc[0][3] += a0 * b3;
      acc[1][0] += a1 * b0; acc[1][1] += a1 * b1; acc[1][2] += a1 * b2; acc[1][3] += a1 * b3;
      acc[2][0] += a2 * b0; acc[2][1] += a2 * b1; acc[2][2] += a2 * b2; acc[2][3] += a2 * b3;
      acc[3][0] += a3 * b0; acc[3][1] += a3 * b1; acc[3][2] += a3 * b2; acc[3][3] += a3 * b3;
    }
    __syncthreads();
  }
#pragma unroll
  for (int r = 0; r < 4; r++) {
    int row = i0 + ty * 4 + r;
    if (row >= M) continue;
#pragma unroll
    for (int c = 0; c < 4; c++) {
      int col = j0 + tx * 4 + c;
      C[(size_t)row * ldc + col] = acc[r][c] + bias[col];
    }
  }
}

// ---------------------------------------------------------------- GRU elementwise
__global__ void gru_update(const float* __restrict__ gi, const float* __restrict__ gh,
                           float* __restrict__ hv) {
  int idx = blockIdx.x * blockDim.x + threadIdx.x;
  if (idx >= N_NODES * H) return;
  int row = idx >> 8, col = idx & 255;
  const float* gir = gi + (size_t)row * G3;
  const float* ghr = gh + (size_t)row * G3;
  float ir = gir[col], iz = gir[H + col], inn = gir[2 * H + col];
  float hr = ghr[col], hz = ghr[H + col], hn = ghr[2 * H + col];
  float r = 1.f / (1.f + expf(-(ir + hr)));
  float z = 1.f / (1.f + expf(-(iz + hz)));
  float n = tanhf(inn + r * hn);
  hv[idx] = (1.f - z) * n + z * hv[idx];
}

// ---------------------------------------------------------------- graph embed phase 1
// U[t][k] = sum_{i: ntype=t} g_i * hv[i][k];   G[t] = sum g_i
__global__ __launch_bounds__(256) void embed_phase1(
    const float* __restrict__ hv, const int* __restrict__ ntype,
    const float* __restrict__ gate_w, const float* __restrict__ gate_b,
    float* __restrict__ U, float* __restrict__ G) {
  __shared__ float Ul[NT * H];
  __shared__ float Gl[NT];
  for (int j = threadIdx.x; j < NT * H; j += 256) Ul[j] = 0.f;
  if (threadIdx.x < NT) Gl[threadIdx.x] = 0.f;
  __syncthreads();
  int lane = threadIdx.x & 63;
  int wave = blockIdx.x * 4 + (threadIdx.x >> 6);
  int nwaves = gridDim.x * 4;
  for (int i = wave; i < N_NODES; i += nwaves) {
    int t = ntype[i];
    float4 h = *reinterpret_cast<const float4*>(hv + (size_t)i * H + lane * 4);
    float4 w = *reinterpret_cast<const float4*>(gate_w + t * H + lane * 4);
    float s = h.x * w.x + h.y * w.y + h.z * w.z + h.w * w.w;
    for (int off = 32; off; off >>= 1) s += __shfl_xor(s, off);
    float g = 1.f / (1.f + expf(-(s + gate_b[t])));
    float* up = Ul + t * H + lane * 4;
    atomicAdd(up + 0, g * h.x);
    atomicAdd(up + 1, g * h.y);
    atomicAdd(up + 2, g * h.z);
    atomicAdd(up + 3, g * h.w);
    if (lane == 0) atomicAdd(&Gl[t], g);
  }
  __syncthreads();
  for (int j = threadIdx.x; j < NT * H; j += 256) unsafeAtomicAdd(&U[j], Ul[j]);
  if (threadIdx.x < NT) unsafeAtomicAdd(&G[threadIdx.x], Gl[threadIdx.x]);
}

// ---------------------------------------------------------------- small heads (1 block)
__global__ __launch_bounds__(512) void small_head(
    const float* __restrict__ U, const float* __restrict__ G,
    const float* __restrict__ tograph_w, const float* __restrict__ tograph_b,
    const float* __restrict__ addnode_w, const float* __restrict__ addnode_b,
    const float* __restrict__ ntype_embed, const float* __restrict__ inithv_w,
    const float* __restrict__ inithv_b, const float* __restrict__ addedge_w,
    const float* __restrict__ addedge_b, const float* __restrict__ hv,
    const float* __restrict__ dest_w, const float* __restrict__ dest_b,
    float* __restrict__ gembed_out, float* __restrict__ nodelogp_out,
    float* __restrict__ hvinit_out, float* __restrict__ edgelogit_out,
    float* __restrict__ misc) {
  __shared__ float ge[GH];
  __shared__ float lg[8];
  int tid = threadIdx.x;
  {  // gembed[j] = sum_t (U[t] @ tograph_w[t])[j] + G[t]*tograph_b[t][j]
    float acc = 0.f;
    for (int t = 0; t < NT; t++) {
      const float* Wt = tograph_w + (size_t)t * H * GH;
      float a2 = 0.f;
      for (int k = 0; k < H; k++) a2 += U[t * H + k] * Wt[(size_t)k * GH + tid];
      acc += a2 + G[t] * tograph_b[t * GH + tid];
    }
    ge[tid] = acc;
    gembed_out[tid] = acc;
  }
  __syncthreads();
  if (tid < 4) {  // node logits
    float l = addnode_b[tid];
    for (int k = 0; k < GH; k++) l += ge[k] * addnode_w[k * 4 + tid];
    lg[tid] = l;
  }
  __syncthreads();
  if (tid == 0) {  // log_softmax over 4
    float m = fmaxf(fmaxf(lg[0], lg[1]), fmaxf(lg[2], lg[3]));
    float s = 0.f;
    for (int c = 0; c < 4; c++) s += expf(lg[c] - m);
    float lse = m + logf(s);
    for (int c = 0; c < 4; c++) nodelogp_out[c] = lg[c] - lse;
  }
  if (tid < H) {  // hv_init = [ntype_embed[0] | gembed] @ inithv_w + b
    float s = inithv_b[tid];
    for (int k = 0; k < H; k++) s += ntype_embed[k] * inithv_w[(size_t)k * H + tid];
    for (int k = 0; k < GH; k++) s += ge[k] * inithv_w[(size_t)(H + k) * H + tid];
    hvinit_out[tid] = s;
  }
  if (tid >= 256 && tid < 320) {  // edge_logit = [gembed | src_embed] . addedge_w + b
    int lane = tid - 256;
    const float* se = hv + (size_t)(N_NODES - 1) * H;
    float s = 0.f;
    for (int k = lane; k < G3; k += 64) {
      float x = (k < GH) ? ge[k] : se[k - GH];
      s += x * addedge_w[k];
    }
    for (int off = 32; off; off >>= 1) s += __shfl_xor(s, off);
    if (lane == 0) edgelogit_out[0] = s + addedge_b[0];
  }
  if (tid >= 320 && tid < 384) {  // c2 = src_embed . dest_w[256:512] + dest_b
    int lane = tid - 320;
    const float* se = hv + (size_t)(N_NODES - 1) * H;
    float s = 0.f;
    for (int k = lane; k < H; k += 64) s += se[k] * dest_w[H + k];
    for (int off = 32; off; off >>= 1) s += __shfl_xor(s, off);
    if (lane == 0) misc[0] = s + dest_b[0];
  }
}

// ---------------------------------------------------------------- dest scores
__global__ __launch_bounds__(256) void dest_scores_kernel(
    const float* __restrict__ hv, const float* __restrict__ dest_w,
    const float* __restrict__ misc, float* __restrict__ scores) {
  int w = (blockIdx.x * blockDim.x + threadIdx.x) >> 6;
  int lane = threadIdx.x & 63;
  if (w >= N_NODES - 1) return;
  float4 h = *reinterpret_cast<const float4*>(hv + (size_t)w * H + lane * 4);
  float4 d = *reinterpret_cast<const float4*>(dest_w + lane * 4);
  float s = h.x * d.x + h.y * d.y + h.z * d.z + h.w * d.w;
  for (int off = 32; off; off >>= 1) s += __shfl_xor(s, off);
  if (lane == 0) scores[w] = s + misc[0];
}

// ---------------------------------------------------------------- dest log_softmax
__global__ __launch_bounds__(1024) void dest_softmax(const float* __restrict__ scores,
                                                     float* __restrict__ out) {
  const int n = N_NODES - 1;
  __shared__ float red[16];
  __shared__ float bc[2];
  int tid = threadIdx.x;
  float m = -1e30f;
  for (int i = tid; i < n; i += 1024) m = fmaxf(m, scores[i]);
  for (int off = 32; off; off >>= 1) m = fmaxf(m, __shfl_xor(m, off));
  if ((tid & 63) == 0) red[tid >> 6] = m;
  __syncthreads();
  if (tid == 0) {
    float v = red[0];
    for (int i = 1; i < 16; i++) v = fmaxf(v, red[i]);
    bc[0] = v;
  }
  __syncthreads();
  float mx = bc[0];
  float s = 0.f;
  for (int i = tid; i < n; i += 1024) s += expf(scores[i] - mx);
  for (int off = 32; off; off >>= 1) s += __shfl_xor(s, off);
  if ((tid & 63) == 0) red[tid >> 6] = s;
  __syncthreads();
  if (tid == 0) {
    float v = 0.f;
    for (int i = 0; i < 16; i++) v += red[i];
    bc[1] = v;
  }
  __syncthreads();
  float lse = mx + logf(bc[1]);
  for (int i = tid; i < n; i += 1024) out[i] = scores[i] - lse;
}

// ---------------------------------------------------------------- launch
extern "C" void kernel_launch(void* const* d_in, const int* in_sizes, int n_in,
                              void* d_out, int out_size, void* d_ws, size_t ws_size,
                              hipStream_t stream) {
  const float* hv0 = (const float*)d_in[0];
  const float* he = (const float*)d_in[1];
  const int* ntype = (const int*)d_in[2];
  const int* src = (const int*)d_in[3];
  const int* dst = (const int*)d_in[4];
  const float* msg_w = (const float*)d_in[5];
  const float* msg_b = (const float*)d_in[6];
  const float* w_ih = (const float*)d_in[7];
  const float* b_ih = (const float*)d_in[8];
  const float* w_hh = (const float*)d_in[9];
  const float* b_hh = (const float*)d_in[10];
  const float* gate_w = (const float*)d_in[11];
  const float* gate_b = (const float*)d_in[12];
  const float* tograph_w = (const float*)d_in[13];
  const float* tograph_b = (const float*)d_in[14];
  const float* addnode_w = (const float*)d_in[15];
  const float* addnode_b = (const float*)d_in[16];
  const float* ntype_embed = (const float*)d_in[17];
  const float* inithv_w = (const float*)d_in[18];
  const float* inithv_b = (const float*)d_in[19];
  const float* addedge_w = (const float*)d_in[20];
  const float* addedge_b = (const float*)d_in[21];
  const float* dest_w = (const float*)d_in[22];
  const float* dest_b = (const float*)d_in[23];

  float* out = (float*)d_out;
  float* HV = out;                                   // N*H (working hv, also output 0)
  float* gembed_out = out + (size_t)N_NODES * H;     // 512
  float* nodelogp_out = gembed_out + GH;             // 4
  float* hvinit_out = nodelogp_out + 4;              // 256
  float* edgelogit_out = hvinit_out + H;             // 1
  float* destlogp_out = edgelogit_out + 1;           // N-1

  float* ws = (float*)d_ws;
  float* S = ws;                                     // N*H
  float* deg = S + (size_t)N_NODES * H;              // N
  float* hesum = deg + N_NODES;                      // N
  float* a_buf = hesum + N_NODES;                    // N*GH
  float* gi = a_buf + (size_t)N_NODES * GH;          // N*G3
  float* gh = gi + (size_t)N_NODES * G3;             // N*G3
  float* U = gh + (size_t)N_NODES * G3;              // NT*H
  float* G = U + NT * H;                             // NT
  float* misc = G + NT;                              // 16
  float* scores = misc + 16;                         // N-1
  int* cnt = (int*)(scores + N_NODES);               // N
  int* rowptr = cnt + N_NODES;                       // N+1
  int* cursor = rowptr + N_NODES + 1;                // N
  int* nbr = cursor + N_NODES;                       // E

  hipMemcpyAsync(HV, hv0, sizeof(float) * (size_t)N_NODES * H,
                 hipMemcpyDeviceToDevice, stream);

  // ---- CSR build (dst is launch-invariant; build once, use both rounds)
  hipMemsetAsync(hesum, 0, sizeof(float) * N_NODES, stream);
  hipMemsetAsync(cnt, 0, sizeof(int) * N_NODES, stream);
  hist_kernel<<<(N_EDGES + 255) / 256, 256, 0, stream>>>(dst, he, cnt, hesum);
  scan_kernel<<<1, 1024, 0, stream>>>(cnt, rowptr, cursor);
  fill_kernel<<<(N_EDGES + 255) / 256, 256, 0, stream>>>(dst, src, cursor, nbr);

  for (int t = 0; t < R_ROUNDS; t++) {
    gather_kernel<<<N_NODES / 4, 256, 0, stream>>>(HV, rowptr, nbr, S, deg);
    {
      dim3 grid(GH / 64, (N_NODES + 63) / 64);
      msg_gemm<<<grid, 256, 0, stream>>>(HV, S, deg, hesum,
                                         msg_w + (size_t)t * (2 * H + 1) * GH,
                                         msg_b + (size_t)t * GH, a_buf);
    }
    {
      dim3 grid(G3 / 64, (N_NODES + 63) / 64);
      gemm_bt_bias<<<grid, 256, 0, stream>>>(N_NODES, G3, GH, a_buf, GH,
                                             w_ih + (size_t)t * G3 * GH,
                                             b_ih + (size_t)t * G3, gi, G3);
      gemm_bt_bias<<<grid, 256, 0, stream>>>(N_NODES, G3, H, HV, H,
                                             w_hh + (size_t)t * G3 * H,
                                             b_hh + (size_t)t * G3, gh, G3);
    }
    gru_update<<<(N_NODES * H + 255) / 256, 256, 0, stream>>>(gi, gh, HV);
  }

  hipMemsetAsync(U, 0, sizeof(float) * (NT * H + NT), stream);
  embed_phase1<<<128, 256, 0, stream>>>(HV, ntype, gate_w, gate_b, U, G);
  small_head<<<1, 512, 0, stream>>>(U, G, tograph_w, tograph_b, addnode_w, addnode_b,
                                    ntype_embed, inithv_w, inithv_b, addedge_w,
                                    addedge_b, HV, dest_w, dest_b, gembed_out,
                                    nodelogp_out, hvinit_out, edgelogit_out, misc);
  dest_scores_kernel<<<((N_NODES - 1) * 64 + 255) / 256, 256, 0, stream>>>(
      HV, dest_w, misc, scores);
  dest_softmax<<<1, 1024, 0, stream>>>(scores, destlogp_out);
}

// Round 4
// 772.036 us; speedup vs baseline: 5.1811x; 2.3920x over previous
//
#include <hip/hip_runtime.h>
#include <math.h>
#include <stdint.h>

#define N_NODES 20000
#define N_EDGES 320000
#define H 256
#define GH 512
#define G3 768
#define NT 3
#define R_ROUNDS 2

typedef __attribute__((ext_vector_type(8))) short short8;
typedef __attribute__((ext_vector_type(8))) unsigned short ushort8;
typedef __attribute__((ext_vector_type(4))) float floatx4;

static __device__ __forceinline__ unsigned short f2bf(float x) {
  unsigned u = __float_as_uint(x);
  u += 0x7fffu + ((u >> 16) & 1u);
  return (unsigned short)(u >> 16);
}

// ---------------------------------------------------------------- CSR build
__global__ __launch_bounds__(256) void hist_kernel(
    const int* __restrict__ dst, const float* __restrict__ he,
    int* __restrict__ cnt, float* __restrict__ hesum) {
  int e = blockIdx.x * 256 + threadIdx.x;
  if (e >= N_EDGES) return;
  int d = dst[e];
  atomicAdd(&cnt[d], 1);
  unsafeAtomicAdd(&hesum[d], he[e]);
}

__global__ __launch_bounds__(1024) void scan_kernel(
    const int* __restrict__ cnt, int* __restrict__ rowptr, int* __restrict__ cursor) {
  __shared__ int part[1024];
  const int CH = (N_NODES + 1023) / 1024;  // 20
  int t = threadIdx.x;
  int base = t * CH;
  int s = 0;
  for (int j = 0; j < CH; j++) {
    int idx = base + j;
    if (idx < N_NODES) s += cnt[idx];
  }
  part[t] = s;
  __syncthreads();
  int v = part[t];
  for (int off = 1; off < 1024; off <<= 1) {
    int o = (t >= off) ? part[t - off] : 0;
    __syncthreads();
    part[t] += o;
    __syncthreads();
  }
  int excl = part[t] - v;
  int run = excl;
  for (int j = 0; j < CH; j++) {
    int idx = base + j;
    if (idx < N_NODES) {
      rowptr[idx] = run;
      cursor[idx] = run;
      run += cnt[idx];
    }
  }
  if (t == 1023) rowptr[N_NODES] = run;
}

__global__ __launch_bounds__(256) void fill_kernel(
    const int* __restrict__ dst, const int* __restrict__ src,
    int* __restrict__ cursor, int* __restrict__ nbr) {
  int e = blockIdx.x * 256 + threadIdx.x;
  if (e >= N_EDGES) return;
  int p = atomicAdd(&cursor[dst[e]], 1);
  nbr[p] = src[e];
}

// ---------------------------------------------------------------- weight prep
__global__ __launch_bounds__(256) void cast_bf16(const float* __restrict__ in,
                                                 unsigned short* __restrict__ out, int n) {
  int i = blockIdx.x * 256 + threadIdx.x;
  if (i < n) out[i] = f2bf(in[i]);
}

// in: 512x512 (k rows, n cols) -> out[n*512+k] = in[k*512+n]
__global__ __launch_bounds__(256) void transpose_cast(const float* __restrict__ in,
                                                      unsigned short* __restrict__ out) {
  int idx = blockIdx.x * 256 + threadIdx.x;
  int n = idx >> 9, k = idx & 511;
  out[idx] = f2bf(in[k * 512 + n]);
}

// ---------------------------------------------------------------- gather
// A_msg[i] = bf16([deg[i]*hv[i] | sum_nbr hv]); HVb[i] = bf16(hv[i]); deg out.
__global__ __launch_bounds__(256) void gather_kernel(
    const float* __restrict__ hv, const int* __restrict__ rowptr,
    const int* __restrict__ nbr, unsigned short* __restrict__ A_msg,
    unsigned short* __restrict__ HVb, float* __restrict__ deg) {
  int w = (blockIdx.x * blockDim.x + threadIdx.x) >> 6;
  int lane = threadIdx.x & 63;
  if (w >= N_NODES) return;
  int start = rowptr[w], end = rowptr[w + 1];
  float4 acc = make_float4(0.f, 0.f, 0.f, 0.f);
  for (int b = start; b < end; b += 64) {
    int nb = min(64, end - b);
    int sidx = (lane < nb) ? nbr[b + lane] : 0;
    for (int j = 0; j < nb; j++) {
      int s = __shfl(sidx, j);
      const float4 v = *reinterpret_cast<const float4*>(hv + (size_t)s * H + lane * 4);
      acc.x += v.x; acc.y += v.y; acc.z += v.z; acc.w += v.w;
    }
  }
  float dg = (float)(end - start);
  const float4 own = *reinterpret_cast<const float4*>(hv + (size_t)w * H + lane * 4);
  ushort4 o;
  o.x = f2bf(own.x * dg); o.y = f2bf(own.y * dg);
  o.z = f2bf(own.z * dg); o.w = f2bf(own.w * dg);
  *reinterpret_cast<ushort4*>(A_msg + (size_t)w * GH + lane * 4) = o;
  o.x = f2bf(acc.x); o.y = f2bf(acc.y); o.z = f2bf(acc.z); o.w = f2bf(acc.w);
  *reinterpret_cast<ushort4*>(A_msg + (size_t)w * GH + H + lane * 4) = o;
  o.x = f2bf(own.x); o.y = f2bf(own.y); o.z = f2bf(own.z); o.w = f2bf(own.w);
  *reinterpret_cast<ushort4*>(HVb + (size_t)w * H + lane * 4) = o;
  if (lane == 0) deg[w] = dg;
}

// ---------------------------------------------------------------- MFMA GEMM
// C[M x Nc] = A[M x K](bf16) @ W[Nc x K](bf16)^T, 128x128 tile, BK=64.
// mode 0: Cf[row*ldc+col] = acc + bias[col]            (fp32 out)
// mode 1: Cb[row*ldc+col] = bf16(acc + hesum[row]*we[col] + deg[row]*bias[col])
// A rows >= M may be read (garbage) but are never stored; buffers have slack.
__global__ __launch_bounds__(256) void mfma_gemm(
    int M, int K,
    const unsigned short* __restrict__ A, const unsigned short* __restrict__ W,
    const float* __restrict__ bias, const float* __restrict__ we,
    const float* __restrict__ deg, const float* __restrict__ hesum,
    float* __restrict__ Cf, unsigned short* __restrict__ Cb, int ldc, int mode) {
  __shared__ unsigned short As[128 * 88];  // row stride 88 shorts (176B, 16B-aligned)
  __shared__ unsigned short Bs[128 * 88];
  int t = threadIdx.x;
  size_t i0 = (size_t)blockIdx.y * 128;
  size_t j0 = (size_t)blockIdx.x * 128;
  int wv = t >> 6, lane = t & 63;
  int m0 = (wv >> 1) * 64, n0 = (wv & 1) * 64;
  int lr = lane & 15, lq = lane >> 4;
  // staging: 8 chunks x 8 shorts = full 64-wide row; 32 rows/pass, 4 passes
  int r0 = t >> 3, kc = t & 7;
  floatx4 acc[4][4];
#pragma unroll
  for (int a = 0; a < 4; a++)
#pragma unroll
    for (int b = 0; b < 4; b++) acc[a][b] = (floatx4){0.f, 0.f, 0.f, 0.f};

  for (int k0 = 0; k0 < K; k0 += 64) {
    ushort8 va[4], vb[4];
#pragma unroll
    for (int p = 0; p < 4; p++) {
      va[p] = *(const ushort8*)(A + (i0 + r0 + p * 32) * K + k0 + kc * 8);
      vb[p] = *(const ushort8*)(W + (j0 + r0 + p * 32) * K + k0 + kc * 8);
    }
    __syncthreads();
#pragma unroll
    for (int p = 0; p < 4; p++) {
      *(ushort8*)(As + (r0 + p * 32) * 88 + kc * 8) = va[p];
      *(ushort8*)(Bs + (r0 + p * 32) * 88 + kc * 8) = vb[p];
    }
    __syncthreads();
#pragma unroll
    for (int kk = 0; kk < 2; kk++) {
      short8 af[4], bf[4];
#pragma unroll
      for (int mi = 0; mi < 4; mi++)
        af[mi] = *(const short8*)(As + (m0 + mi * 16 + lr) * 88 + kk * 32 + lq * 8);
#pragma unroll
      for (int ni = 0; ni < 4; ni++)
        bf[ni] = *(const short8*)(Bs + (n0 + ni * 16 + lr) * 88 + kk * 32 + lq * 8);
#pragma unroll
      for (int mi = 0; mi < 4; mi++)
#pragma unroll
        for (int ni = 0; ni < 4; ni++)
          acc[mi][ni] = __builtin_amdgcn_mfma_f32_16x16x32_bf16(af[mi], bf[ni],
                                                                acc[mi][ni], 0, 0, 0);
    }
  }

  if (mode == 0) {
#pragma unroll
    for (int mi = 0; mi < 4; mi++) {
#pragma unroll
      for (int ni = 0; ni < 4; ni++) {
        int col = (int)j0 + n0 + ni * 16 + lr;
        float bv = bias[col];
#pragma unroll
        for (int i = 0; i < 4; i++) {
          size_t row = i0 + m0 + mi * 16 + lq * 4 + i;
          if (row < (size_t)M) Cf[row * ldc + col] = acc[mi][ni][i] + bv;
        }
      }
    }
  } else {
#pragma unroll
    for (int mi = 0; mi < 4; mi++) {
#pragma unroll
      for (int ni = 0; ni < 4; ni++) {
        int col = (int)j0 + n0 + ni * 16 + lr;
        float wv_ = we[col], bv = bias[col];
#pragma unroll
        for (int i = 0; i < 4; i++) {
          size_t row = i0 + m0 + mi * 16 + lq * 4 + i;
          if (row < (size_t)M)
            Cb[row * ldc + col] = f2bf(acc[mi][ni][i] + hesum[row] * wv_ + deg[row] * bv);
        }
      }
    }
  }
}

// ---------------------------------------------------------------- GRU elementwise
__global__ void gru_update(const float* __restrict__ gi, const float* __restrict__ gh,
                           float* __restrict__ hv) {
  int idx = blockIdx.x * blockDim.x + threadIdx.x;
  if (idx >= N_NODES * H) return;
  int row = idx >> 8, col = idx & 255;
  const float* gir = gi + (size_t)row * G3;
  const float* ghr = gh + (size_t)row * G3;
  float ir = gir[col], iz = gir[H + col], inn = gir[2 * H + col];
  float hr = ghr[col], hz = ghr[H + col], hn = ghr[2 * H + col];
  float r = 1.f / (1.f + expf(-(ir + hr)));
  float z = 1.f / (1.f + expf(-(iz + hz)));
  float n = tanhf(inn + r * hn);
  hv[idx] = (1.f - z) * n + z * hv[idx];
}

// ---------------------------------------------------------------- graph embed phase 1
__global__ __launch_bounds__(256) void embed_phase1(
    const float* __restrict__ hv, const int* __restrict__ ntype,
    const float* __restrict__ gate_w, const float* __restrict__ gate_b,
    float* __restrict__ U, float* __restrict__ G) {
  __shared__ float Ul[NT * H];
  __shared__ float Gl[NT];
  for (int j = threadIdx.x; j < NT * H; j += 256) Ul[j] = 0.f;
  if (threadIdx.x < NT) Gl[threadIdx.x] = 0.f;
  __syncthreads();
  int lane = threadIdx.x & 63;
  int wave = blockIdx.x * 4 + (threadIdx.x >> 6);
  int nwaves = gridDim.x * 4;
  for (int i = wave; i < N_NODES; i += nwaves) {
    int t = ntype[i];
    float4 h = *reinterpret_cast<const float4*>(hv + (size_t)i * H + lane * 4);
    float4 w = *reinterpret_cast<const float4*>(gate_w + t * H + lane * 4);
    float s = h.x * w.x + h.y * w.y + h.z * w.z + h.w * w.w;
    for (int off = 32; off; off >>= 1) s += __shfl_xor(s, off);
    float g = 1.f / (1.f + expf(-(s + gate_b[t])));
    float* up = Ul + t * H + lane * 4;
    atomicAdd(up + 0, g * h.x);
    atomicAdd(up + 1, g * h.y);
    atomicAdd(up + 2, g * h.z);
    atomicAdd(up + 3, g * h.w);
    if (lane == 0) atomicAdd(&Gl[t], g);
  }
  __syncthreads();
  for (int j = threadIdx.x; j < NT * H; j += 256) unsafeAtomicAdd(&U[j], Ul[j]);
  if (threadIdx.x < NT) unsafeAtomicAdd(&G[threadIdx.x], Gl[threadIdx.x]);
}

// ---------------------------------------------------------------- small heads
__global__ __launch_bounds__(512) void small_head(
    const float* __restrict__ U, const float* __restrict__ G,
    const float* __restrict__ tograph_w, const float* __restrict__ tograph_b,
    const float* __restrict__ addnode_w, const float* __restrict__ addnode_b,
    const float* __restrict__ ntype_embed, const float* __restrict__ inithv_w,
    const float* __restrict__ inithv_b, const float* __restrict__ addedge_w,
    const float* __restrict__ addedge_b, const float* __restrict__ hv,
    const float* __restrict__ dest_w, const float* __restrict__ dest_b,
    float* __restrict__ gembed_out, float* __restrict__ nodelogp_out,
    float* __restrict__ hvinit_out, float* __restrict__ edgelogit_out,
    float* __restrict__ misc) {
  __shared__ float ge[GH];
  __shared__ float lg[8];
  int tid = threadIdx.x;
  {
    float acc = 0.f;
    for (int t = 0; t < NT; t++) {
      const float* Wt = tograph_w + (size_t)t * H * GH;
      float a2 = 0.f;
      for (int k = 0; k < H; k++) a2 += U[t * H + k] * Wt[(size_t)k * GH + tid];
      acc += a2 + G[t] * tograph_b[t * GH + tid];
    }
    ge[tid] = acc;
    gembed_out[tid] = acc;
  }
  __syncthreads();
  if (tid < 4) {
    float l = addnode_b[tid];
    for (int k = 0; k < GH; k++) l += ge[k] * addnode_w[k * 4 + tid];
    lg[tid] = l;
  }
  __syncthreads();
  if (tid == 0) {
    float m = fmaxf(fmaxf(lg[0], lg[1]), fmaxf(lg[2], lg[3]));
    float s = 0.f;
    for (int c = 0; c < 4; c++) s += expf(lg[c] - m);
    float lse = m + logf(s);
    for (int c = 0; c < 4; c++) nodelogp_out[c] = lg[c] - lse;
  }
  if (tid < H) {
    float s = inithv_b[tid];
    for (int k = 0; k < H; k++) s += ntype_embed[k] * inithv_w[(size_t)k * H + tid];
    for (int k = 0; k < GH; k++) s += ge[k] * inithv_w[(size_t)(H + k) * H + tid];
    hvinit_out[tid] = s;
  }
  if (tid >= 256 && tid < 320) {
    int lane = tid - 256;
    const float* se = hv + (size_t)(N_NODES - 1) * H;
    float s = 0.f;
    for (int k = lane; k < G3; k += 64) {
      float x = (k < GH) ? ge[k] : se[k - GH];
      s += x * addedge_w[k];
    }
    for (int off = 32; off; off >>= 1) s += __shfl_xor(s, off);
    if (lane == 0) edgelogit_out[0] = s + addedge_b[0];
  }
  if (tid >= 320 && tid < 384) {
    int lane = tid - 320;
    const float* se = hv + (size_t)(N_NODES - 1) * H;
    float s = 0.f;
    for (int k = lane; k < H; k += 64) s += se[k] * dest_w[H + k];
    for (int off = 32; off; off >>= 1) s += __shfl_xor(s, off);
    if (lane == 0) misc[0] = s + dest_b[0];
  }
}

// ---------------------------------------------------------------- dest scores
__global__ __launch_bounds__(256) void dest_scores_kernel(
    const float* __restrict__ hv, const float* __restrict__ dest_w,
    const float* __restrict__ misc, float* __restrict__ scores) {
  int w = (blockIdx.x * blockDim.x + threadIdx.x) >> 6;
  int lane = threadIdx.x & 63;
  if (w >= N_NODES - 1) return;
  float4 h = *reinterpret_cast<const float4*>(hv + (size_t)w * H + lane * 4);
  float4 d = *reinterpret_cast<const float4*>(dest_w + lane * 4);
  float s = h.x * d.x + h.y * d.y + h.z * d.z + h.w * d.w;
  for (int off = 32; off; off >>= 1) s += __shfl_xor(s, off);
  if (lane == 0) scores[w] = s + misc[0];
}

__global__ __launch_bounds__(1024) void dest_softmax(const float* __restrict__ scores,
                                                     float* __restrict__ out) {
  const int n = N_NODES - 1;
  __shared__ float red[16];
  __shared__ float bc[2];
  int tid = threadIdx.x;
  float m = -1e30f;
  for (int i = tid; i < n; i += 1024) m = fmaxf(m, scores[i]);
  for (int off = 32; off; off >>= 1) m = fmaxf(m, __shfl_xor(m, off));
  if ((tid & 63) == 0) red[tid >> 6] = m;
  __syncthreads();
  if (tid == 0) {
    float v = red[0];
    for (int i = 1; i < 16; i++) v = fmaxf(v, red[i]);
    bc[0] = v;
  }
  __syncthreads();
  float mx = bc[0];
  float s = 0.f;
  for (int i = tid; i < n; i += 1024) s += expf(scores[i] - mx);
  for (int off = 32; off; off >>= 1) s += __shfl_xor(s, off);
  if ((tid & 63) == 0) red[tid >> 6] = s;
  __syncthreads();
  if (tid == 0) {
    float v = 0.f;
    for (int i = 0; i < 16; i++) v += red[i];
    bc[1] = v;
  }
  __syncthreads();
  float lse = mx + logf(bc[1]);
  for (int i = tid; i < n; i += 1024) out[i] = scores[i] - lse;
}

// ---------------------------------------------------------------- launch
extern "C" void kernel_launch(void* const* d_in, const int* in_sizes, int n_in,
                              void* d_out, int out_size, void* d_ws, size_t ws_size,
                              hipStream_t stream) {
  const float* hv0 = (const float*)d_in[0];
  const float* he = (const float*)d_in[1];
  const int* ntype = (const int*)d_in[2];
  const int* src = (const int*)d_in[3];
  const int* dst = (const int*)d_in[4];
  const float* msg_w = (const float*)d_in[5];
  const float* msg_b = (const float*)d_in[6];
  const float* w_ih = (const float*)d_in[7];
  const float* b_ih = (const float*)d_in[8];
  const float* w_hh = (const float*)d_in[9];
  const float* b_hh = (const float*)d_in[10];
  const float* gate_w = (const float*)d_in[11];
  const float* gate_b = (const float*)d_in[12];
  const float* tograph_w = (const float*)d_in[13];
  const float* tograph_b = (const float*)d_in[14];
  const float* addnode_w = (const float*)d_in[15];
  const float* addnode_b = (const float*)d_in[16];
  const float* ntype_embed = (const float*)d_in[17];
  const float* inithv_w = (const float*)d_in[18];
  const float* inithv_b = (const float*)d_in[19];
  const float* addedge_w = (const float*)d_in[20];
  const float* addedge_b = (const float*)d_in[21];
  const float* dest_w = (const float*)d_in[22];
  const float* dest_b = (const float*)d_in[23];

  float* out = (float*)d_out;
  float* HV = out;
  float* gembed_out = out + (size_t)N_NODES * H;
  float* nodelogp_out = gembed_out + GH;
  float* hvinit_out = nodelogp_out + 4;
  float* edgelogit_out = hvinit_out + H;
  float* destlogp_out = edgelogit_out + 1;

  float* ws = (float*)d_ws;
  float* deg = ws;                                    // N
  float* hesum = deg + N_NODES;                       // N
  float* gi = hesum + N_NODES;                        // N*G3
  float* gh = gi + (size_t)N_NODES * G3;              // N*G3
  float* U = gh + (size_t)N_NODES * G3;               // NT*H
  float* G = U + NT * H;                              // NT
  float* misc = G + NT;                               // 16
  float* scores = misc + 16;                          // N
  int* cnt = (int*)(scores + N_NODES);                // N
  int* rowptr = cnt + N_NODES;                        // N+1
  int* cursor = rowptr + N_NODES + 1;                 // N
  int* nbr = cursor + N_NODES;                        // E
  unsigned short* A_msg =
      (unsigned short*)(((uintptr_t)(nbr + N_EDGES) + 15) & ~(uintptr_t)15);
  unsigned short* HVb = A_msg + (size_t)(N_NODES + 128) * GH;
  unsigned short* a_b = HVb + (size_t)(N_NODES + 128) * H;
  unsigned short* wihb = a_b + (size_t)(N_NODES + 128) * GH;
  unsigned short* whhb = wihb + (size_t)2 * G3 * GH;
  unsigned short* Wmt = whhb + (size_t)2 * G3 * H;

  hipMemcpyAsync(HV, hv0, sizeof(float) * (size_t)N_NODES * H,
                 hipMemcpyDeviceToDevice, stream);

  // ---- weight prep (bf16; msg_w transposed to N x K)
  cast_bf16<<<(2 * G3 * GH + 255) / 256, 256, 0, stream>>>(w_ih, wihb, 2 * G3 * GH);
  cast_bf16<<<(2 * G3 * H + 255) / 256, 256, 0, stream>>>(w_hh, whhb, 2 * G3 * H);
  transpose_cast<<<(512 * 512) / 256, 256, 0, stream>>>(msg_w, Wmt);
  transpose_cast<<<(512 * 512) / 256, 256, 0, stream>>>(msg_w + 513 * 512,
                                                        Wmt + 512 * 512);

  // ---- CSR build
  hipMemsetAsync(hesum, 0, sizeof(float) * N_NODES, stream);
  hipMemsetAsync(cnt, 0, sizeof(int) * N_NODES, stream);
  hist_kernel<<<(N_EDGES + 255) / 256, 256, 0, stream>>>(dst, he, cnt, hesum);
  scan_kernel<<<1, 1024, 0, stream>>>(cnt, rowptr, cursor);
  fill_kernel<<<(N_EDGES + 255) / 256, 256, 0, stream>>>(dst, src, cursor, nbr);

  const int MB = (N_NODES + 127) / 128;  // 157
  for (int t = 0; t < R_ROUNDS; t++) {
    gather_kernel<<<N_NODES / 4, 256, 0, stream>>>(HV, rowptr, nbr, A_msg, HVb, deg);
    // msg: a = [deg*hv | S] @ Wm + hesum*we + deg*bm  -> bf16 a_b
    mfma_gemm<<<dim3(GH / 128, MB), 256, 0, stream>>>(
        N_NODES, GH, A_msg, Wmt + (size_t)t * GH * GH, msg_b + (size_t)t * GH,
        msg_w + (size_t)t * (2 * H + 1) * GH + (size_t)GH * GH, deg, hesum,
        nullptr, a_b, GH, 1);
    // gi = a @ w_ih^T + b_ih
    mfma_gemm<<<dim3(G3 / 128, MB), 256, 0, stream>>>(
        N_NODES, GH, a_b, wihb + (size_t)t * G3 * GH, b_ih + (size_t)t * G3,
        nullptr, nullptr, nullptr, gi, nullptr, G3, 0);
    // gh = hv @ w_hh^T + b_hh
    mfma_gemm<<<dim3(G3 / 128, MB), 256, 0, stream>>>(
        N_NODES, H, HVb, whhb + (size_t)t * G3 * H, b_hh + (size_t)t * G3,
        nullptr, nullptr, nullptr, gh, nullptr, G3, 0);
    gru_update<<<(N_NODES * H + 255) / 256, 256, 0, stream>>>(gi, gh, HV);
  }

  hipMemsetAsync(U, 0, sizeof(float) * (NT * H + NT), stream);
  embed_phase1<<<128, 256, 0, stream>>>(HV, ntype, gate_w, gate_b, U, G);
  small_head<<<1, 512, 0, stream>>>(U, G, tograph_w, tograph_b, addnode_w, addnode_b,
                                    ntype_embed, inithv_w, inithv_b, addedge_w,
                                    addedge_b, HV, dest_w, dest_b, gembed_out,
                                    nodelogp_out, hvinit_out, edgelogit_out, misc);
  dest_scores_kernel<<<((N_NODES - 1) * 64 + 255) / 256, 256, 0, stream>>>(
      HV, dest_w, misc, scores);
  dest_softmax<<<1, 1024, 0, stream>>>(scores, destlogp_out);
}